// Round 16
// baseline (121.741 us; speedup 1.0000x reference)
//
#include <hip/hip_runtime.h>
#include <math.h>

// Problem dims (fixed)
#define TT 4
#define BB 8
#define CC 384
#define HWN 1024      // 32*32
#define NHEAD 12
#define CHD 32        // C / heads
#define C2 768        // 2*C
#define LL 64         // 8*8 patches
#define KCONV 6144    // C*4*4
#define KB_TOT 192    // KCONV/32
#define MROWS 2048    // TT*BB*64

#define K2INV ((_Float16)4.8828125e-4f)   // 2^-11, exact

typedef _Float16 f16x8 __attribute__((ext_vector_type(8)));
typedef _Float16 f16x4 __attribute__((ext_vector_type(4)));
typedef float f32x4 __attribute__((ext_vector_type(4)));

#if defined(__has_builtin)
#if __has_builtin(__builtin_amdgcn_global_load_lds)
#define USE_GLL 1
#endif
#if __has_builtin(__builtin_amdgcn_sched_barrier)
#define HAVE_SCHEDBAR 1
#endif
#if __has_builtin(__builtin_amdgcn_s_setprio)
#define HAVE_SETPRIO 1
#endif
#endif
#ifndef USE_GLL
#define USE_GLL 0
#endif
#ifndef HAVE_SCHEDBAR
#define HAVE_SCHEDBAR 0
#endif
#ifndef HAVE_SETPRIO
#define HAVE_SETPRIO 0
#endif

#if HAVE_SCHEDBAR
#define SCHED_FENCE() __builtin_amdgcn_sched_barrier(0)
#else
#define SCHED_FENCE()
#endif

#if HAVE_SETPRIO
#define PRIO_HI() __builtin_amdgcn_s_setprio(1)
#define PRIO_LO() __builtin_amdgcn_s_setprio(0)
#else
#define PRIO_HI()
#define PRIO_LO()
#endif

#if USE_GLL
typedef __attribute__((address_space(3))) unsigned int lds_uint;
typedef const __attribute__((address_space(1))) unsigned int glob_uint;
__device__ __forceinline__ void load_lds16(const void* g, void* l) {
    __builtin_amdgcn_global_load_lds((glob_uint*)g, (lds_uint*)l, 16, 0, 0);
}
#endif

// ---------------- K0: pack w_conv (hi/lo) + w_proj, merged single launch ----------------
__global__ __launch_bounds__(256) void k_pack_all(const float* __restrict__ w,
                                                  const float* __restrict__ wp,
                                                  _Float16* __restrict__ W0,
                                                  _Float16* __restrict__ W1,
                                                  _Float16* __restrict__ WpH) {
    __shared__ __align__(16) _Float16 Lh[4096];
    __shared__ __align__(16) _Float16 Ll[4096];
    int b = blockIdx.x;
    int tid = threadIdx.x;
    int r0 = tid >> 3;            // 0..31
    int c4 = (tid & 7) * 4;       // 0..28
    int q = c4 >> 3, j0 = c4 & 7;
    if (b < 1152) {
        int kb = b / 6, nb = b - kb * 6;
#pragma unroll
        for (int ri = 0; ri < 4; ri++) {
            int col = ri * 32 + r0;
            const float* src = w + (size_t)(nb * 128 + col) * KCONV + kb * 32 + c4;
            float4 v = *(const float4*)src;
            float vv[4] = {v.x, v.y, v.z, v.w};
#pragma unroll
            for (int e = 0; e < 4; e++) {
                _Float16 h = (_Float16)vv[e];
                float rem = (vv[e] - (float)h) * 2048.0f;
                Lh[q * 1024 + col * 8 + j0 + e] = h;
                Ll[q * 1024 + col * 8 + j0 + e] = (_Float16)rem;
            }
        }
        __syncthreads();
        size_t o = ((size_t)kb * 6 + nb) * 4096 + tid * 16;
        *(f16x8*)(W0 + o) = *(const f16x8*)&Lh[tid * 16];
        *(f16x8*)(W0 + o + 8) = *(const f16x8*)&Lh[tid * 16 + 8];
        *(f16x8*)(W1 + o) = *(const f16x8*)&Ll[tid * 16];
        *(f16x8*)(W1 + o + 8) = *(const f16x8*)&Ll[tid * 16 + 8];
    } else {
        int bb = b - 1152;
        int kb = bb / 3, ot = bb - kb * 3;
#pragma unroll
        for (int ri = 0; ri < 4; ri++) {
            int col = ri * 32 + r0;
            const float* src = wp + (size_t)(ot * 128 + col) * CC + kb * 32 + c4;
            float4 v = *(const float4*)src;
            float vv[4] = {v.x, v.y, v.z, v.w};
#pragma unroll
            for (int e = 0; e < 4; e++)
                Lh[q * 1024 + col * 8 + j0 + e] = (_Float16)vv[e];
        }
        __syncthreads();
        size_t o = ((size_t)kb * 3 + ot) * 4096 + tid * 16;
        *(f16x8*)(WpH + o) = *(const f16x8*)&Lh[tid * 16];
        *(f16x8*)(WpH + o + 8) = *(const f16x8*)&Lh[tid * 16 + 8];
    }
}

// ---------------- K1: LIF over T on x -> xsC + xsF. Single-stage LDS (1 barrier) ----------------
__global__ __launch_bounds__(256) void k_lif1(const float* __restrict__ x,
                                              _Float16* __restrict__ xsC,
                                              _Float16* __restrict__ xsF) {
    __shared__ __align__(16) _Float16 S[4][4][4][16][8];   // [t][okb][oqc][row][j] = 16 KB
    int nt = blockIdx.x & 3, q8 = blockIdx.x >> 2;
    int bh = blockIdx.y;
    int b = bh / NHEAD, hh = bh % NHEAD;
    int tid = threadIdx.x;
    int n = nt * 256 + tid;
    const int stride = BB * CC * HWN;
    int h = n >> 5, w = n & 31;
    int a = h & 3, pj = w >> 2, bp = w & 3;
    int qa = a >> 1;
    int jc = (a & 1) * 4 + bp;
    int rowloc = ((h >> 2) & 1) * 8 + pj;     // 0..15
    size_t base0 = ((size_t)b * CC + hh * 32 + q8 * 8) * HWN + n;
    f16x8 frag[4];
#pragma unroll
    for (int j = 0; j < 8; j++) {
        float v = 0.0f;
        size_t off = base0 + (size_t)j * HWN;
#pragma unroll
        for (int t = 0; t < TT; t++) {
            float xv = x[(size_t)t * stride + off];
            v += (xv - v) * 0.5f;
            float s = (v >= 1.0f) ? 1.0f : 0.0f;
            if (s > 0.0f) v = 0.0f;
            frag[t][j] = (_Float16)s;
        }
    }
    // xsF: attn B-frag layout
#pragma unroll
    for (int t = 0; t < TT; t++) {
        int tb = t * BB + b;
        size_t dst = ((size_t)(tb * NHEAD + hh) * 8 + (n >> 7)) * 4096 + q8 * 1024 + (size_t)(n & 127) * 8;
        *(f16x8*)(xsF + dst) = frag[t];
    }
    // xsC: stage all 4 t-tiles in LDS, single barrier, coalesced stores
#pragma unroll
    for (int t = 0; t < TT; t++)
#pragma unroll
        for (int j = 0; j < 8; j++)
            S[t][j >> 1][(j & 1) * 2 + qa][rowloc][jc] = frag[t][j];
    __syncthreads();
    int kb0 = hh * 16 + q8 * 4;
    int okb = tid >> 6, oqc = (tid >> 4) & 3, orow = tid & 15;
#pragma unroll
    for (int t = 0; t < TT; t++) {
        int tb = t * BB + b;
        int mt = tb >> 1;
        int row = (tb & 1) * 64 + nt * 16 + orow;
        _Float16* dst = xsC + (size_t)mt * (192 * 4096) + (size_t)(kb0 + okb) * 4096 + oqc * 1024 + (size_t)row * 8;
        *(f16x8*)dst = *(const f16x8*)&S[t][okb][oqc][orow][0];
    }
}

// ---------------- K2: conv-as-GEMM via f16 MFMA, unified hi/lo accumulator ----------------
// Counted-vmcnt pipeline (T4) + setprio around MFMA cluster (T5). [R13-best, unchanged]
__global__ __launch_bounds__(256, 3) void k_conv_mfma(const _Float16* __restrict__ xsC,
                                                      const _Float16* __restrict__ W0,
                                                      const _Float16* __restrict__ W1,
                                                      float* __restrict__ P,
                                                      int KS, int kbPerSplit) {
    __shared__ __align__(16) _Float16 As[2][4096];   // 16 KB spikes
    __shared__ __align__(16) _Float16 Bh[2][4096];   // 16 KB W hi
    __shared__ __align__(16) _Float16 Bl[2][4096];   // 16 KB W lo

    int bid = blockIdx.x;
    int s = bid % KS;
    int idx = bid / KS;          // 0..95
    int mt = idx & 15;
    int nt = idx >> 4;           // 0..5
    int kb0 = s * kbPerSplit;
    int tid = threadIdx.x;
    int wave = tid >> 6;
    int lane = tid & 63;
    int l16 = lane & 15, lq = lane >> 4;
    int wr = (wave & 1) * 64, wc = (wave >> 1) * 64;   // wr: m-range, wc: oc-range

    f32x4 acc[4][4];   // [fi=oc frag][fj=m frag]
#pragma unroll
    for (int i = 0; i < 4; i++)
#pragma unroll
        for (int j = 0; j < 4; j++) acc[i][j] = (f32x4){0.f, 0.f, 0.f, 0.f};

    const char* aBase = (const char*)xsC + (size_t)mt * (192 * 8192);
    const char* b0Base = (const char*)W0 + (size_t)nt * 8192;
    const char* b1Base = (const char*)W1 + (size_t)nt * 8192;
    int wo = wave * 2048;
    int lo16 = lane * 16;

#if USE_GLL
#define STAGE(buf, kb) do {                                              \
    const char* aS = aBase + (size_t)(kb) * 8192;                        \
    const char* b0S = b0Base + (size_t)(kb) * (6 * 8192);                \
    const char* b1S = b1Base + (size_t)(kb) * (6 * 8192);                \
    load_lds16(aS + wo + lo16, (char*)As[buf] + wo);                     \
    load_lds16(aS + wo + 1024 + lo16, (char*)As[buf] + wo + 1024);       \
    load_lds16(b0S + wo + lo16, (char*)Bh[buf] + wo);                    \
    load_lds16(b0S + wo + 1024 + lo16, (char*)Bh[buf] + wo + 1024);      \
    load_lds16(b1S + wo + lo16, (char*)Bl[buf] + wo);                    \
    load_lds16(b1S + wo + 1024 + lo16, (char*)Bl[buf] + wo + 1024);      \
} while (0)

    // prologue: 2 tiles in flight (12 loads)
    STAGE(0, kb0);
    if (kbPerSplit > 1) STAGE(1, kb0 + 1);
    int cur = 0;
    for (int i = 0; i < kbPerSplit; ++i) {
        if (i < kbPerSplit - 1)
            asm volatile("s_waitcnt vmcnt(6)" ::: "memory");
        else
            asm volatile("s_waitcnt vmcnt(0)" ::: "memory");
        __builtin_amdgcn_s_barrier();
        SCHED_FENCE();

        f16x8 wfh[4], wfl[4], sf[4], sfs[4];
#pragma unroll
        for (int fj = 0; fj < 4; fj++)
            sf[fj] = *(const f16x8*)&As[cur][(size_t)(lq * 128 + wr + fj * 16 + l16) * 8];
#pragma unroll
        for (int fi = 0; fi < 4; fi++) {
            wfh[fi] = *(const f16x8*)&Bh[cur][(size_t)(lq * 128 + wc + fi * 16 + l16) * 8];
            wfl[fi] = *(const f16x8*)&Bl[cur][(size_t)(lq * 128 + wc + fi * 16 + l16) * 8];
        }
        asm volatile("s_waitcnt lgkmcnt(0)" ::: "memory");
        SCHED_FENCE();
        __builtin_amdgcn_s_barrier();     // all waves have their frags; buf reusable
        SCHED_FENCE();
        if (i + 2 < kbPerSplit) STAGE(cur, kb0 + i + 2);
        SCHED_FENCE();

#pragma unroll
        for (int fj = 0; fj < 4; fj++) sfs[fj] = sf[fj] * K2INV;   // exact: {0, 2^-11}
        PRIO_HI();
#pragma unroll
        for (int fi = 0; fi < 4; fi++)
#pragma unroll
            for (int fj = 0; fj < 4; fj++)
                acc[fi][fj] = __builtin_amdgcn_mfma_f32_16x16x32_f16(wfh[fi], sf[fj], acc[fi][fj], 0, 0, 0);
#pragma unroll
        for (int fi = 0; fi < 4; fi++)
#pragma unroll
            for (int fj = 0; fj < 4; fj++)
                acc[fi][fj] = __builtin_amdgcn_mfma_f32_16x16x32_f16(wfl[fi], sfs[fj], acc[fi][fj], 0, 0, 0);
        PRIO_LO();

        cur ^= 1;
    }
#undef STAGE
#else
#define STAGE(buf, kb) do {                                              \
    const char* aS = aBase + (size_t)(kb) * 8192;                        \
    const char* b0S = b0Base + (size_t)(kb) * (6 * 8192);                \
    const char* b1S = b1Base + (size_t)(kb) * (6 * 8192);                \
    _Pragma("unroll")                                                    \
    for (int i_ = 0; i_ < 2; ++i_) {                                     \
        int off_ = wo + i_ * 1024 + lo16;                                \
        *(float4*)((char*)As[buf] + off_) = *(const float4*)(aS + off_); \
        *(float4*)((char*)Bh[buf] + off_) = *(const float4*)(b0S + off_);\
        *(float4*)((char*)Bl[buf] + off_) = *(const float4*)(b1S + off_);\
    }                                                                    \
} while (0)
    STAGE(0, kb0);
    __syncthreads();
    int cur = 0;
    for (int i = 0; i < kbPerSplit; ++i) {
        if (i + 1 < kbPerSplit) STAGE(cur ^ 1, kb0 + i + 1);
        f16x8 wfh[4], wfl[4], sf[4], sfs[4];
#pragma unroll
        for (int fj = 0; fj < 4; fj++) {
            sf[fj] = *(const f16x8*)&As[cur][(size_t)(lq * 128 + wr + fj * 16 + l16) * 8];
            sfs[fj] = sf[fj] * K2INV;
        }
#pragma unroll
        for (int fi = 0; fi < 4; fi++) {
            wfh[fi] = *(const f16x8*)&Bh[cur][(size_t)(lq * 128 + wc + fi * 16 + l16) * 8];
            wfl[fi] = *(const f16x8*)&Bl[cur][(size_t)(lq * 128 + wc + fi * 16 + l16) * 8];
        }
#pragma unroll
        for (int fi = 0; fi < 4; fi++)
#pragma unroll
            for (int fj = 0; fj < 4; fj++)
                acc[fi][fj] = __builtin_amdgcn_mfma_f32_16x16x32_f16(wfh[fi], sf[fj], acc[fi][fj], 0, 0, 0);
#pragma unroll
        for (int fi = 0; fi < 4; fi++)
#pragma unroll
            for (int fj = 0; fj < 4; fj++)
                acc[fi][fj] = __builtin_amdgcn_mfma_f32_16x16x32_f16(wfl[fi], sfs[fj], acc[fi][fj], 0, 0, 0);
        __syncthreads();
        cur ^= 1;
    }
#undef STAGE
#endif

    // P store: float4 over 4 consecutive oc (r-index)
    size_t Pbase = (size_t)s * MROWS * C2;
#pragma unroll
    for (int fi = 0; fi < 4; fi++) {
        int oc0 = nt * 128 + wc + fi * 16 + lq * 4;
#pragma unroll
        for (int fj = 0; fj < 4; fj++) {
            int m = mt * 128 + wr + fj * 16 + l16;
            *(f32x4*)(P + Pbase + (size_t)m * C2 + oc0) = acc[fi][fj];
        }
    }
}

// ---------------- K2b: reduce split-K + BN1 -> A1/A2 hi-lo f16 fragments per (tb,hh) ----------------
__global__ __launch_bounds__(256) void k_reduce_frag(const float* __restrict__ P,
                                                     const float* __restrict__ g1,
                                                     const float* __restrict__ b1,
                                                     const float* __restrict__ m1,
                                                     const float* __restrict__ v1,
                                                     _Float16* __restrict__ A1,
                                                     _Float16* __restrict__ A2,
                                                     int KS) {
    __shared__ float y2ls[32][66];
    int tb = blockIdx.x / NHEAD, hh = blockIdx.x % NHEAD;
    int tid = threadIdx.x;
    int pp = tid >> 2, cq = (tid & 3) * 16;

    size_t rowbase = ((size_t)tb * 64 + pp) * C2 + hh * 64 + cq;
    float yv[16];
#pragma unroll
    for (int i = 0; i < 16; i++) yv[i] = 0.0f;
    for (int s = 0; s < KS; s++) {
        const float* p = P + (size_t)s * MROWS * C2 + rowbase;
#pragma unroll
        for (int i4 = 0; i4 < 4; i4++) {
            float4 v = *(const float4*)(p + i4 * 4);
            yv[i4 * 4 + 0] += v.x;
            yv[i4 * 4 + 1] += v.y;
            yv[i4 * 4 + 2] += v.z;
            yv[i4 * 4 + 3] += v.w;
        }
    }
#pragma unroll
    for (int i = 0; i < 16; i++) {
        int oc = hh * 64 + cq + i;
        float inv = g1[oc] / sqrtf(v1[oc] + 1e-5f);
        yv[i] = (yv[i] - m1[oc]) * inv + b1[oc];
    }

    size_t reg = (size_t)(tb * NHEAD + hh) * 4096;
    if (cq < 32) {
#pragma unroll
        for (int gi = 0; gi < 2; gi++) {
            int c0 = cq + gi * 8;
            f16x8 h, l;
#pragma unroll
            for (int j = 0; j < 8; j++) {
                float v = yv[gi * 8 + j];
                _Float16 hi = (_Float16)v;
                h[j] = hi;
                l[j] = (_Float16)((v - (float)hi) * 2048.0f);
            }
            size_t a = reg + (size_t)(((pp >> 4) * 4 + (c0 >> 3)) * 128 + (pp & 15) * 8);
            *(f16x8*)(A1 + a) = h;
            *(f16x8*)(A1 + a + 2048) = l;
        }
    } else {
#pragma unroll
        for (int i = 0; i < 16; i++) y2ls[cq - 32 + i][pp] = yv[i];
    }
    __syncthreads();
    int d16 = tid & 15, grp = tid >> 4;
    f16x8 h, l;
#pragma unroll
    for (int j = 0; j < 8; j++) {
        float v = y2ls[(grp >> 3) * 16 + d16][((grp >> 2) & 1) * 32 + (grp & 3) * 8 + j];
        _Float16 hi = (_Float16)v;
        h[j] = hi;
        l[j] = (_Float16)((v - (float)hi) * 2048.0f);
    }
    size_t a = reg + (size_t)((grp * 16 + d16) * 8);
    *(f16x8*)(A2 + a) = h;
    *(f16x8*)(A2 + a + 2048) = l;
}

// ---------------- K3: fused attention via MFMA; Bs+Sat double-buffered, 1 barrier per t ----------------
__global__ __launch_bounds__(256, 3) void k_attn_mfma(const _Float16* __restrict__ xsF,
                                                      const _Float16* __restrict__ A1,
                                                      const _Float16* __restrict__ A2,
                                                      const float* __restrict__ fr_x,
                                                      const float* __restrict__ fr_attn,
                                                      _Float16* __restrict__ OsF) {
    __shared__ __align__(16) _Float16 Bs[2][4096];    // 16 KB xr tile dbuf
    __shared__ __align__(16) _Float16 Sat[2][8192];   // 32 KB attn spike dbuf

    int nt = blockIdx.x;
    int bh = blockIdx.y;
    int b = bh / NHEAD, hh = bh % NHEAD;
    int tid = threadIdx.x;
    int w = tid >> 6;
    int lane = tid & 63;
    int l16 = lane & 15, lq = lane >> 4;

    float scale1 = 1.0f / sqrtf(fr_x[hh] * 32.0f);
    float scale2 = 1.0f / sqrtf(fr_attn[hh] * 64.0f);

    float va[8][4];
    float vo[2][2][4];
#pragma unroll
    for (int nf = 0; nf < 8; nf++)
#pragma unroll
        for (int r = 0; r < 4; r++) va[nf][r] = 0.0f;
#pragma unroll
    for (int dt = 0; dt < 2; dt++)
#pragma unroll
        for (int nf = 0; nf < 2; nf++)
#pragma unroll
            for (int r = 0; r < 4; r++) vo[dt][nf][r] = 0.0f;

#if USE_GLL
#define ASTAGE(buf, treg) do {                                                        \
    const char* src_ = (const char*)(xsF + ((size_t)(treg) * 8 + nt) * 4096);         \
    load_lds16(src_ + tid * 16, (char*)Bs[buf] + tid * 16);                           \
    load_lds16(src_ + tid * 16 + 4096, (char*)Bs[buf] + tid * 16 + 4096);             \
} while (0)
#else
#define ASTAGE(buf, treg) do {                                                        \
    const char* src_ = (const char*)(xsF + ((size_t)(treg) * 8 + nt) * 4096);         \
    *(float4*)((char*)Bs[buf] + tid * 16) = *(const float4*)(src_ + tid * 16);        \
    *(float4*)((char*)Bs[buf] + tid * 16 + 4096) = *(const float4*)(src_ + tid * 16 + 4096); \
} while (0)
#endif

    // prologue: stage t=0 tile; full drain barrier
    ASTAGE(0, (size_t)(0 * BB + b) * NHEAD + hh);
    __syncthreads();

    int cur = 0;
    for (int t = 0; t < TT; t++) {
        int tb = t * BB + b;
        size_t reg = (size_t)(tb * NHEAD + hh);
        const _Float16* a1b = A1 + reg * 4096;
        f16x8 a1h = *(const f16x8*)(a1b + (size_t)(((w * 4 + lq) * 16 + l16) * 8));
        f16x8 a1l = *(const f16x8*)(a1b + 2048 + (size_t)(((w * 4 + lq) * 16 + l16) * 8));
        f16x8 a1ls = a1l * K2INV;    // exact exponent shift (normal range)
        // issue next-t stage into other buffer (WAR cleared by previous mid-barrier)
        if (t + 1 < TT) ASTAGE(cur ^ 1, (size_t)((t + 1) * BB + b) * NHEAD + hh);

        f32x4 ah[8];
#pragma unroll
        for (int nf = 0; nf < 8; nf++) ah[nf] = (f32x4){0.f, 0.f, 0.f, 0.f};
        PRIO_HI();
#pragma unroll
        for (int nf = 0; nf < 8; nf++) {
            f16x8 bf = *(const f16x8*)&Bs[cur][(size_t)(nf * 16 + l16) * 8 + lq * 1024];
            ah[nf] = __builtin_amdgcn_mfma_f32_16x16x32_f16(a1h, bf, ah[nf], 0, 0, 0);
            ah[nf] = __builtin_amdgcn_mfma_f32_16x16x32_f16(a1ls, bf, ah[nf], 0, 0, 0);
        }
        PRIO_LO();
        int pq = w * 2 + (lq >> 1);
#pragma unroll
        for (int nf = 0; nf < 8; nf++) {
            f16x4 sp;
#pragma unroll
            for (int r = 0; r < 4; r++) {
                float a = ah[nf][r] * scale1;
                float v = va[nf][r];
                v += (a - v) * 0.5f;
                float s = (v >= 1.0f) ? 1.0f : 0.0f;
                va[nf][r] = (s > 0.0f) ? 0.0f : v;
                sp[r] = (_Float16)s;
            }
            *(f16x4*)&Sat[cur][(size_t)(pq * 128 + nf * 16 + l16) * 8 + (lq & 1) * 4] = sp;
        }
        __syncthreads();   // full drain: Sat RAW + next-Bs GLL landed + prior-Bs WAR

        const _Float16* a2b = A2 + reg * 4096;
        f32x4 oh[2][2];
#pragma unroll
        for (int dt = 0; dt < 2; dt++)
#pragma unroll
            for (int nf = 0; nf < 2; nf++) oh[dt][nf] = (f32x4){0.f, 0.f, 0.f, 0.f};
        PRIO_HI();
#pragma unroll
        for (int ks = 0; ks < 2; ks++) {
            f16x8 bf0 = *(const f16x8*)&Sat[cur][(size_t)((ks * 4 + lq) * 128 + w * 32 + l16) * 8];
            f16x8 bf1 = *(const f16x8*)&Sat[cur][(size_t)((ks * 4 + lq) * 128 + w * 32 + 16 + l16) * 8];
#pragma unroll
            for (int dt = 0; dt < 2; dt++) {
                size_t ao = (size_t)(((dt * 8 + ks * 4 + lq) * 16 + l16) * 8);
                f16x8 a2h = *(const f16x8*)(a2b + ao);
                f16x8 a2ls = *(const f16x8*)(a2b + 2048 + ao) * K2INV;
                oh[dt][0] = __builtin_amdgcn_mfma_f32_16x16x32_f16(a2h, bf0, oh[dt][0], 0, 0, 0);
                oh[dt][0] = __builtin_amdgcn_mfma_f32_16x16x32_f16(a2ls, bf0, oh[dt][0], 0, 0, 0);
                oh[dt][1] = __builtin_amdgcn_mfma_f32_16x16x32_f16(a2h, bf1, oh[dt][1], 0, 0, 0);
                oh[dt][1] = __builtin_amdgcn_mfma_f32_16x16x32_f16(a2ls, bf1, oh[dt][1], 0, 0, 0);
            }
        }
        PRIO_LO();
        _Float16* og = OsF + (reg * 8 + nt) * 4096;
#pragma unroll
        for (int dt = 0; dt < 2; dt++)
#pragma unroll
            for (int nf = 0; nf < 2; nf++) {
                f16x4 sp;
#pragma unroll
                for (int r = 0; r < 4; r++) {
                    float a = oh[dt][nf][r] * scale2;
                    float v = vo[dt][nf][r];
                    v += (a - v) * 0.5f;
                    float s = (v >= 1.0f) ? 1.0f : 0.0f;
                    vo[dt][nf][r] = (s > 0.0f) ? 0.0f : v;
                    sp[r] = (_Float16)s;
                }
                int n = w * 32 + nf * 16 + l16;
                *(f16x4*)(og + (size_t)((dt * 2 + (lq >> 1)) * 1024 + n * 8 + (lq & 1) * 4)) = sp;
            }
        cur ^= 1;   // no trailing barrier: Sat WAR cleared by next iter's mid-barrier
    }
#undef ASTAGE
}

// ---------------- K4: projection GEMM via MFMA + BN2 + residual -> d_out ----------------
__global__ __launch_bounds__(256, 3) void k_proj_mfma(const _Float16* __restrict__ OsF,
                                                      const _Float16* __restrict__ WpH,
                                                      const float* __restrict__ g2,
                                                      const float* __restrict__ b2,
                                                      const float* __restrict__ m2,
                                                      const float* __restrict__ vv2,
                                                      const float* __restrict__ x,
                                                      float* __restrict__ out) {
    __shared__ __align__(16) _Float16 Bs[2][4096];   // 16 KB spike dbuf

    int bid = blockIdx.x;
    int xcd = bid & 7;
    int idx = bid >> 3;              // 0..95
    int tb = xcd * 4 + idx / 24;
    int rem = idx % 24;
    int nt = rem & 7;
    int ot = rem >> 3;               // 0..2
    int tid = threadIdx.x;
    int wave = tid >> 6;
    int lane = tid & 63;
    int l16 = lane & 15, lq = lane >> 4;
    int wn = (wave & 1) * 64, wo = (wave >> 1) * 64;   // wn: n-range, wo: o-range

    f32x4 acc[4][4];   // [fn][fo]
#pragma unroll
    for (int i = 0; i < 4; i++)
#pragma unroll
        for (int j = 0; j < 4; j++) acc[i][j] = (f32x4){0.f, 0.f, 0.f, 0.f};

    const char* bBase = (const char*)(OsF + ((size_t)tb * NHEAD * 8 + nt) * 4096);
    const _Float16* aBase = WpH + (size_t)ot * 4096 + lq * 1024 + (size_t)(wo + l16) * 8;
    int halfo = wave * 2048;
    int lo16 = lane * 16;

#if USE_GLL
#define PSTAGE(buf, kb) do {                                                   \
    const char* bS = bBase + (size_t)(kb) * (8 * 8192);                        \
    load_lds16(bS + halfo + lo16, (char*)Bs[buf] + halfo);                     \
    load_lds16(bS + halfo + 1024 + lo16, (char*)Bs[buf] + halfo + 1024);       \
} while (0)
#else
#define PSTAGE(buf, kb) do {                                                   \
    const char* bS = bBase + (size_t)(kb) * (8 * 8192);                        \
    _Pragma("unroll")                                                          \
    for (int i_ = 0; i_ < 2; ++i_) {                                           \
        int off_ = halfo + i_ * 1024 + lo16;                                   \
        *(float4*)((char*)Bs[buf] + off_) = *(const float4*)(bS + off_);       \
    }                                                                          \
} while (0)
#endif

    f16x8 af[4], afn[4];
#pragma unroll
    for (int fo = 0; fo < 4; fo++) af[fo] = *(const f16x8*)(aBase + (size_t)(fo * 16) * 8);
    PSTAGE(0, 0);
    __syncthreads();

    int cur = 0;
    for (int kb = 0; kb < 12; ++kb) {
        int kbn = (kb + 1 < 12) ? kb + 1 : kb;
        if (kb + 1 < 12) PSTAGE(cur ^ 1, kb + 1);
        const _Float16* an = aBase + (size_t)kbn * (3 * 4096);
#pragma unroll
        for (int fo = 0; fo < 4; fo++) afn[fo] = *(const f16x8*)(an + (size_t)(fo * 16) * 8);

        f16x8 bf[4];
#pragma unroll
        for (int fn = 0; fn < 4; fn++)
            bf[fn] = *(const f16x8*)&Bs[cur][(size_t)(lq * 128 + wn + fn * 16 + l16) * 8];
        PRIO_HI();
#pragma unroll
        for (int fn = 0; fn < 4; fn++)
#pragma unroll
            for (int fo = 0; fo < 4; fo++)
                acc[fn][fo] = __builtin_amdgcn_mfma_f32_16x16x32_f16(bf[fn], af[fo], acc[fn][fo], 0, 0, 0);
        PRIO_LO();

        __syncthreads();
        cur ^= 1;
#pragma unroll
        for (int fo = 0; fo < 4; fo++) af[fo] = afn[fo];
    }
#undef PSTAGE

    // epilogue: BN2 + residual, float4 over 4 consecutive n (r-index)
    size_t orow_base = (size_t)tb * CC * HWN;
#pragma unroll
    for (int fo = 0; fo < 4; fo++) {
        int o = ot * 128 + wo + fo * 16 + l16;
        float inv = g2[o] / sqrtf(vv2[o] + 1e-5f);
        float mu = m2[o];
        float bt = b2[o];
        size_t obase = orow_base + (size_t)o * HWN;
#pragma unroll
        for (int fn = 0; fn < 4; fn++) {
            size_t addr = obase + (size_t)(nt * 128 + wn + fn * 16 + lq * 4);
            float4 xv = *(const float4*)(x + addr);
            f32x4 a = acc[fn][fo];
            float4 ov;
            ov.x = (a[0] - mu) * inv + bt + xv.x;
            ov.y = (a[1] - mu) * inv + bt + xv.y;
            ov.z = (a[2] - mu) * inv + bt + xv.z;
            ov.w = (a[3] - mu) * inv + bt + xv.w;
            *(float4*)(out + addr) = ov;
        }
    }
}

extern "C" void kernel_launch(void* const* d_in, const int* in_sizes, int n_in,
                              void* d_out, int out_size, void* d_ws, size_t ws_size,
                              hipStream_t stream) {
    const float* x = (const float*)d_in[0];
    const float* w_conv = (const float*)d_in[1];
    const float* bn1_gamma = (const float*)d_in[2];
    const float* bn1_beta = (const float*)d_in[3];
    const float* bn1_mean = (const float*)d_in[4];
    const float* bn1_var = (const float*)d_in[5];
    const float* w_proj = (const float*)d_in[6];
    const float* bn2_gamma = (const float*)d_in[7];
    const float* bn2_beta = (const float*)d_in[8];
    const float* bn2_mean = (const float*)d_in[9];
    const float* bn2_var = (const float*)d_in[10];
    const float* fr_x = (const float*)d_in[11];
    const float* fr_attn = (const float*)d_in[12];

    // workspace layout
    const size_t FRAG = (size_t)16 * 192 * 4096 * 2;              // 25,165,824 (xsC; also xsF/OsF size)
    const size_t AB = (size_t)TT * BB * NHEAD * 4096 * 2;         // 3,145,728 (A1 / A2)
    const size_t WB = (size_t)KCONV * C2 * 2;                     // 9,437,184
    const size_t WPB = (size_t)CC * CC * 2;                       // 294,912
    const size_t PB = (size_t)MROWS * C2 * 4;                     // 6,291,456 per split
    _Float16* xsC = (_Float16*)d_ws;
    _Float16* xsF = (_Float16*)((char*)xsC + FRAG);
    _Float16* OsF = (_Float16*)((char*)xsF + FRAG);
    _Float16* A1 = (_Float16*)((char*)OsF + FRAG);
    _Float16* A2 = (_Float16*)((char*)A1 + AB);
    _Float16* W0 = (_Float16*)((char*)A2 + AB);
    _Float16* W1 = (_Float16*)((char*)W0 + WB);
    _Float16* WpH = (_Float16*)((char*)W1 + WB);
    char* tail = (char*)WpH + WPB;

    int KS;
    float* P;
    if (ws_size >= (size_t)(tail - (char*)d_ws) + 8 * PB) {
        KS = 8;
        P = (float*)tail;
    } else if (ws_size >= (size_t)(tail - (char*)d_ws) + 4 * PB) {
        KS = 4;
        P = (float*)tail;
    } else {
        KS = 2;                    // alias P onto OsF region (OsF written later by k_attn)
        P = (float*)OsF;
    }
    int kbPerSplit = KB_TOT / KS;

    k_pack_all<<<1188, 256, 0, stream>>>(w_conv, w_proj, W0, W1, WpH);
    k_lif1<<<dim3(16, BB * NHEAD), 256, 0, stream>>>(x, xsC, xsF);
    k_conv_mfma<<<96 * KS, 256, 0, stream>>>(xsC, W0, W1, P, KS, kbPerSplit);
    k_reduce_frag<<<32 * NHEAD, 256, 0, stream>>>(P, bn1_gamma, bn1_beta, bn1_mean, bn1_var, A1, A2, KS);
    k_attn_mfma<<<dim3(8, BB * NHEAD), 256, 0, stream>>>(xsF, A1, A2, fr_x, fr_attn, OsF);
    k_proj_mfma<<<768, 256, 0, stream>>>(OsF, WpH, bn2_gamma, bn2_beta, bn2_mean, bn2_var, x, (float*)d_out);
}

// Round 17
// 119.582 us; speedup vs baseline: 1.0181x; 1.0181x over previous
//
#include <hip/hip_runtime.h>
#include <math.h>

// Problem dims (fixed)
#define TT 4
#define BB 8
#define CC 384
#define HWN 1024      // 32*32
#define NHEAD 12
#define CHD 32        // C / heads
#define C2 768        // 2*C
#define LL 64         // 8*8 patches
#define KCONV 6144    // C*4*4
#define KB_TOT 192    // KCONV/32
#define MROWS 2048    // TT*BB*64

#define K2INV ((_Float16)4.8828125e-4f)   // 2^-11, exact

typedef _Float16 f16x8 __attribute__((ext_vector_type(8)));
typedef _Float16 f16x4 __attribute__((ext_vector_type(4)));
typedef float f32x4 __attribute__((ext_vector_type(4)));

#if defined(__has_builtin)
#if __has_builtin(__builtin_amdgcn_global_load_lds)
#define USE_GLL 1
#endif
#if __has_builtin(__builtin_amdgcn_sched_barrier)
#define HAVE_SCHEDBAR 1
#endif
#if __has_builtin(__builtin_amdgcn_s_setprio)
#define HAVE_SETPRIO 1
#endif
#endif
#ifndef USE_GLL
#define USE_GLL 0
#endif
#ifndef HAVE_SCHEDBAR
#define HAVE_SCHEDBAR 0
#endif
#ifndef HAVE_SETPRIO
#define HAVE_SETPRIO 0
#endif

#if HAVE_SCHEDBAR
#define SCHED_FENCE() __builtin_amdgcn_sched_barrier(0)
#else
#define SCHED_FENCE()
#endif

#if HAVE_SETPRIO
#define PRIO_HI() __builtin_amdgcn_s_setprio(1)
#define PRIO_LO() __builtin_amdgcn_s_setprio(0)
#else
#define PRIO_HI()
#define PRIO_LO()
#endif

#if USE_GLL
typedef __attribute__((address_space(3))) unsigned int lds_uint;
typedef const __attribute__((address_space(1))) unsigned int glob_uint;
__device__ __forceinline__ void load_lds16(const void* g, void* l) {
    __builtin_amdgcn_global_load_lds((glob_uint*)g, (lds_uint*)l, 16, 0, 0);
}
#endif

// ---------------- K0: pack w_conv (hi/lo) + w_proj, merged single launch ----------------
__global__ __launch_bounds__(256) void k_pack_all(const float* __restrict__ w,
                                                  const float* __restrict__ wp,
                                                  _Float16* __restrict__ W0,
                                                  _Float16* __restrict__ W1,
                                                  _Float16* __restrict__ WpH) {
    __shared__ __align__(16) _Float16 Lh[4096];
    __shared__ __align__(16) _Float16 Ll[4096];
    int b = blockIdx.x;
    int tid = threadIdx.x;
    int r0 = tid >> 3;            // 0..31
    int c4 = (tid & 7) * 4;       // 0..28
    int q = c4 >> 3, j0 = c4 & 7;
    if (b < 1152) {
        int kb = b / 6, nb = b - kb * 6;
#pragma unroll
        for (int ri = 0; ri < 4; ri++) {
            int col = ri * 32 + r0;
            const float* src = w + (size_t)(nb * 128 + col) * KCONV + kb * 32 + c4;
            float4 v = *(const float4*)src;
            float vv[4] = {v.x, v.y, v.z, v.w};
#pragma unroll
            for (int e = 0; e < 4; e++) {
                _Float16 h = (_Float16)vv[e];
                float rem = (vv[e] - (float)h) * 2048.0f;
                Lh[q * 1024 + col * 8 + j0 + e] = h;
                Ll[q * 1024 + col * 8 + j0 + e] = (_Float16)rem;
            }
        }
        __syncthreads();
        size_t o = ((size_t)kb * 6 + nb) * 4096 + tid * 16;
        *(f16x8*)(W0 + o) = *(const f16x8*)&Lh[tid * 16];
        *(f16x8*)(W0 + o + 8) = *(const f16x8*)&Lh[tid * 16 + 8];
        *(f16x8*)(W1 + o) = *(const f16x8*)&Ll[tid * 16];
        *(f16x8*)(W1 + o + 8) = *(const f16x8*)&Ll[tid * 16 + 8];
    } else {
        int bb = b - 1152;
        int kb = bb / 3, ot = bb - kb * 3;
#pragma unroll
        for (int ri = 0; ri < 4; ri++) {
            int col = ri * 32 + r0;
            const float* src = wp + (size_t)(ot * 128 + col) * CC + kb * 32 + c4;
            float4 v = *(const float4*)src;
            float vv[4] = {v.x, v.y, v.z, v.w};
#pragma unroll
            for (int e = 0; e < 4; e++)
                Lh[q * 1024 + col * 8 + j0 + e] = (_Float16)vv[e];
        }
        __syncthreads();
        size_t o = ((size_t)kb * 3 + ot) * 4096 + tid * 16;
        *(f16x8*)(WpH + o) = *(const f16x8*)&Lh[tid * 16];
        *(f16x8*)(WpH + o + 8) = *(const f16x8*)&Lh[tid * 16 + 8];
    }
}

// ---------------- K1: LIF over T on x -> xsC + xsF. Single-stage LDS (1 barrier) ----------------
__global__ __launch_bounds__(256) void k_lif1(const float* __restrict__ x,
                                              _Float16* __restrict__ xsC,
                                              _Float16* __restrict__ xsF) {
    __shared__ __align__(16) _Float16 S[4][4][4][16][8];   // [t][okb][oqc][row][j] = 16 KB
    int nt = blockIdx.x & 3, q8 = blockIdx.x >> 2;
    int bh = blockIdx.y;
    int b = bh / NHEAD, hh = bh % NHEAD;
    int tid = threadIdx.x;
    int n = nt * 256 + tid;
    const int stride = BB * CC * HWN;
    int h = n >> 5, w = n & 31;
    int a = h & 3, pj = w >> 2, bp = w & 3;
    int qa = a >> 1;
    int jc = (a & 1) * 4 + bp;
    int rowloc = ((h >> 2) & 1) * 8 + pj;     // 0..15
    size_t base0 = ((size_t)b * CC + hh * 32 + q8 * 8) * HWN + n;
    f16x8 frag[4];
#pragma unroll
    for (int j = 0; j < 8; j++) {
        float v = 0.0f;
        size_t off = base0 + (size_t)j * HWN;
#pragma unroll
        for (int t = 0; t < TT; t++) {
            float xv = x[(size_t)t * stride + off];
            v += (xv - v) * 0.5f;
            float s = (v >= 1.0f) ? 1.0f : 0.0f;
            if (s > 0.0f) v = 0.0f;
            frag[t][j] = (_Float16)s;
        }
    }
    // xsF: attn B-frag layout
#pragma unroll
    for (int t = 0; t < TT; t++) {
        int tb = t * BB + b;
        size_t dst = ((size_t)(tb * NHEAD + hh) * 8 + (n >> 7)) * 4096 + q8 * 1024 + (size_t)(n & 127) * 8;
        *(f16x8*)(xsF + dst) = frag[t];
    }
    // xsC: stage all 4 t-tiles in LDS, single barrier, coalesced stores
#pragma unroll
    for (int t = 0; t < TT; t++)
#pragma unroll
        for (int j = 0; j < 8; j++)
            S[t][j >> 1][(j & 1) * 2 + qa][rowloc][jc] = frag[t][j];
    __syncthreads();
    int kb0 = hh * 16 + q8 * 4;
    int okb = tid >> 6, oqc = (tid >> 4) & 3, orow = tid & 15;
#pragma unroll
    for (int t = 0; t < TT; t++) {
        int tb = t * BB + b;
        int mt = tb >> 1;
        int row = (tb & 1) * 64 + nt * 16 + orow;
        _Float16* dst = xsC + (size_t)mt * (192 * 4096) + (size_t)(kb0 + okb) * 4096 + oqc * 1024 + (size_t)row * 8;
        *(f16x8*)dst = *(const f16x8*)&S[t][okb][oqc][orow][0];
    }
}

// ---------------- K2: conv-as-GEMM via f16 MFMA, unified hi/lo accumulator ----------------
// Counted-vmcnt pipeline (T4) + setprio around MFMA cluster (T5). [session-best config]
__global__ __launch_bounds__(256, 3) void k_conv_mfma(const _Float16* __restrict__ xsC,
                                                      const _Float16* __restrict__ W0,
                                                      const _Float16* __restrict__ W1,
                                                      float* __restrict__ P,
                                                      int KS, int kbPerSplit) {
    __shared__ __align__(16) _Float16 As[2][4096];   // 16 KB spikes
    __shared__ __align__(16) _Float16 Bh[2][4096];   // 16 KB W hi
    __shared__ __align__(16) _Float16 Bl[2][4096];   // 16 KB W lo

    int bid = blockIdx.x;
    int s = bid % KS;
    int idx = bid / KS;          // 0..95
    int mt = idx & 15;
    int nt = idx >> 4;           // 0..5
    int kb0 = s * kbPerSplit;
    int tid = threadIdx.x;
    int wave = tid >> 6;
    int lane = tid & 63;
    int l16 = lane & 15, lq = lane >> 4;
    int wr = (wave & 1) * 64, wc = (wave >> 1) * 64;   // wr: m-range, wc: oc-range

    f32x4 acc[4][4];   // [fi=oc frag][fj=m frag]
#pragma unroll
    for (int i = 0; i < 4; i++)
#pragma unroll
        for (int j = 0; j < 4; j++) acc[i][j] = (f32x4){0.f, 0.f, 0.f, 0.f};

    const char* aBase = (const char*)xsC + (size_t)mt * (192 * 8192);
    const char* b0Base = (const char*)W0 + (size_t)nt * 8192;
    const char* b1Base = (const char*)W1 + (size_t)nt * 8192;
    int wo = wave * 2048;
    int lo16 = lane * 16;

#if USE_GLL
#define STAGE(buf, kb) do {                                              \
    const char* aS = aBase + (size_t)(kb) * 8192;                        \
    const char* b0S = b0Base + (size_t)(kb) * (6 * 8192);                \
    const char* b1S = b1Base + (size_t)(kb) * (6 * 8192);                \
    load_lds16(aS + wo + lo16, (char*)As[buf] + wo);                     \
    load_lds16(aS + wo + 1024 + lo16, (char*)As[buf] + wo + 1024);       \
    load_lds16(b0S + wo + lo16, (char*)Bh[buf] + wo);                    \
    load_lds16(b0S + wo + 1024 + lo16, (char*)Bh[buf] + wo + 1024);      \
    load_lds16(b1S + wo + lo16, (char*)Bl[buf] + wo);                    \
    load_lds16(b1S + wo + 1024 + lo16, (char*)Bl[buf] + wo + 1024);      \
} while (0)

    // prologue: 2 tiles in flight (12 loads)
    STAGE(0, kb0);
    if (kbPerSplit > 1) STAGE(1, kb0 + 1);
    int cur = 0;
    for (int i = 0; i < kbPerSplit; ++i) {
        if (i < kbPerSplit - 1)
            asm volatile("s_waitcnt vmcnt(6)" ::: "memory");
        else
            asm volatile("s_waitcnt vmcnt(0)" ::: "memory");
        __builtin_amdgcn_s_barrier();
        SCHED_FENCE();

        f16x8 wfh[4], wfl[4], sf[4], sfs[4];
#pragma unroll
        for (int fj = 0; fj < 4; fj++)
            sf[fj] = *(const f16x8*)&As[cur][(size_t)(lq * 128 + wr + fj * 16 + l16) * 8];
#pragma unroll
        for (int fi = 0; fi < 4; fi++) {
            wfh[fi] = *(const f16x8*)&Bh[cur][(size_t)(lq * 128 + wc + fi * 16 + l16) * 8];
            wfl[fi] = *(const f16x8*)&Bl[cur][(size_t)(lq * 128 + wc + fi * 16 + l16) * 8];
        }
        asm volatile("s_waitcnt lgkmcnt(0)" ::: "memory");
        SCHED_FENCE();
        __builtin_amdgcn_s_barrier();     // all waves have their frags; buf reusable
        SCHED_FENCE();
        if (i + 2 < kbPerSplit) STAGE(cur, kb0 + i + 2);
        SCHED_FENCE();

#pragma unroll
        for (int fj = 0; fj < 4; fj++) sfs[fj] = sf[fj] * K2INV;   // exact: {0, 2^-11}
        PRIO_HI();
#pragma unroll
        for (int fi = 0; fi < 4; fi++)
#pragma unroll
            for (int fj = 0; fj < 4; fj++)
                acc[fi][fj] = __builtin_amdgcn_mfma_f32_16x16x32_f16(wfh[fi], sf[fj], acc[fi][fj], 0, 0, 0);
#pragma unroll
        for (int fi = 0; fi < 4; fi++)
#pragma unroll
            for (int fj = 0; fj < 4; fj++)
                acc[fi][fj] = __builtin_amdgcn_mfma_f32_16x16x32_f16(wfl[fi], sfs[fj], acc[fi][fj], 0, 0, 0);
        PRIO_LO();

        cur ^= 1;
    }
#undef STAGE
#else
#define STAGE(buf, kb) do {                                              \
    const char* aS = aBase + (size_t)(kb) * 8192;                        \
    const char* b0S = b0Base + (size_t)(kb) * (6 * 8192);                \
    const char* b1S = b1Base + (size_t)(kb) * (6 * 8192);                \
    _Pragma("unroll")                                                    \
    for (int i_ = 0; i_ < 2; ++i_) {                                     \
        int off_ = wo + i_ * 1024 + lo16;                                \
        *(float4*)((char*)As[buf] + off_) = *(const float4*)(aS + off_); \
        *(float4*)((char*)Bh[buf] + off_) = *(const float4*)(b0S + off_);\
        *(float4*)((char*)Bl[buf] + off_) = *(const float4*)(b1S + off_);\
    }                                                                    \
} while (0)
    STAGE(0, kb0);
    __syncthreads();
    int cur = 0;
    for (int i = 0; i < kbPerSplit; ++i) {
        if (i + 1 < kbPerSplit) STAGE(cur ^ 1, kb0 + i + 1);
        f16x8 wfh[4], wfl[4], sf[4], sfs[4];
#pragma unroll
        for (int fj = 0; fj < 4; fj++) {
            sf[fj] = *(const f16x8*)&As[cur][(size_t)(lq * 128 + wr + fj * 16 + l16) * 8];
            sfs[fj] = sf[fj] * K2INV;
        }
#pragma unroll
        for (int fi = 0; fi < 4; fi++) {
            wfh[fi] = *(const f16x8*)&Bh[cur][(size_t)(lq * 128 + wc + fi * 16 + l16) * 8];
            wfl[fi] = *(const f16x8*)&Bl[cur][(size_t)(lq * 128 + wc + fi * 16 + l16) * 8];
        }
#pragma unroll
        for (int fi = 0; fi < 4; fi++)
#pragma unroll
            for (int fj = 0; fj < 4; fj++)
                acc[fi][fj] = __builtin_amdgcn_mfma_f32_16x16x32_f16(wfh[fi], sf[fj], acc[fi][fj], 0, 0, 0);
#pragma unroll
        for (int fi = 0; fi < 4; fi++)
#pragma unroll
            for (int fj = 0; fj < 4; fj++)
                acc[fi][fj] = __builtin_amdgcn_mfma_f32_16x16x32_f16(wfl[fi], sfs[fj], acc[fi][fj], 0, 0, 0);
        __syncthreads();
        cur ^= 1;
    }
#undef STAGE
#endif

    // P store: float4 over 4 consecutive oc (r-index)
    size_t Pbase = (size_t)s * MROWS * C2;
#pragma unroll
    for (int fi = 0; fi < 4; fi++) {
        int oc0 = nt * 128 + wc + fi * 16 + lq * 4;
#pragma unroll
        for (int fj = 0; fj < 4; fj++) {
            int m = mt * 128 + wr + fj * 16 + l16;
            *(f32x4*)(P + Pbase + (size_t)m * C2 + oc0) = acc[fi][fj];
        }
    }
}

// ---------------- K2b: reduce split-K + BN1 -> A1/A2 hi-lo f16 fragments per (tb,hh) ----------------
__global__ __launch_bounds__(256) void k_reduce_frag(const float* __restrict__ P,
                                                     const float* __restrict__ g1,
                                                     const float* __restrict__ b1,
                                                     const float* __restrict__ m1,
                                                     const float* __restrict__ v1,
                                                     _Float16* __restrict__ A1,
                                                     _Float16* __restrict__ A2,
                                                     int KS) {
    __shared__ float y2ls[32][66];
    int tb = blockIdx.x / NHEAD, hh = blockIdx.x % NHEAD;
    int tid = threadIdx.x;
    int pp = tid >> 2, cq = (tid & 3) * 16;

    size_t rowbase = ((size_t)tb * 64 + pp) * C2 + hh * 64 + cq;
    float yv[16];
#pragma unroll
    for (int i = 0; i < 16; i++) yv[i] = 0.0f;
    for (int s = 0; s < KS; s++) {
        const float* p = P + (size_t)s * MROWS * C2 + rowbase;
#pragma unroll
        for (int i4 = 0; i4 < 4; i4++) {
            float4 v = *(const float4*)(p + i4 * 4);
            yv[i4 * 4 + 0] += v.x;
            yv[i4 * 4 + 1] += v.y;
            yv[i4 * 4 + 2] += v.z;
            yv[i4 * 4 + 3] += v.w;
        }
    }
#pragma unroll
    for (int i = 0; i < 16; i++) {
        int oc = hh * 64 + cq + i;
        float inv = g1[oc] / sqrtf(v1[oc] + 1e-5f);
        yv[i] = (yv[i] - m1[oc]) * inv + b1[oc];
    }

    size_t reg = (size_t)(tb * NHEAD + hh) * 4096;
    if (cq < 32) {
#pragma unroll
        for (int gi = 0; gi < 2; gi++) {
            int c0 = cq + gi * 8;
            f16x8 h, l;
#pragma unroll
            for (int j = 0; j < 8; j++) {
                float v = yv[gi * 8 + j];
                _Float16 hi = (_Float16)v;
                h[j] = hi;
                l[j] = (_Float16)((v - (float)hi) * 2048.0f);
            }
            size_t a = reg + (size_t)(((pp >> 4) * 4 + (c0 >> 3)) * 128 + (pp & 15) * 8);
            *(f16x8*)(A1 + a) = h;
            *(f16x8*)(A1 + a + 2048) = l;
        }
    } else {
#pragma unroll
        for (int i = 0; i < 16; i++) y2ls[cq - 32 + i][pp] = yv[i];
    }
    __syncthreads();
    int d16 = tid & 15, grp = tid >> 4;
    f16x8 h, l;
#pragma unroll
    for (int j = 0; j < 8; j++) {
        float v = y2ls[(grp >> 3) * 16 + d16][((grp >> 2) & 1) * 32 + (grp & 3) * 8 + j];
        _Float16 hi = (_Float16)v;
        h[j] = hi;
        l[j] = (_Float16)((v - (float)hi) * 2048.0f);
    }
    size_t a = reg + (size_t)((grp * 16 + d16) * 8);
    *(f16x8*)(A2 + a) = h;
    *(f16x8*)(A2 + a + 2048) = l;
}

// ---------------- K3: fused attention via MFMA, unified hi/lo accumulators -> OsF ----------------
__global__ __launch_bounds__(256, 3) void k_attn_mfma(const _Float16* __restrict__ xsF,
                                                      const _Float16* __restrict__ A1,
                                                      const _Float16* __restrict__ A2,
                                                      const float* __restrict__ fr_x,
                                                      const float* __restrict__ fr_attn,
                                                      _Float16* __restrict__ OsF) {
    __shared__ __align__(16) _Float16 Bs[4][128][8];    // 8 KB xr tile
    __shared__ __align__(16) _Float16 Sat[8][128][8];   // 16 KB attn spikes

    int nt = blockIdx.x;
    int bh = blockIdx.y;
    int b = bh / NHEAD, hh = bh % NHEAD;
    int tid = threadIdx.x;
    int w = tid >> 6;
    int lane = tid & 63;
    int l16 = lane & 15, lq = lane >> 4;

    float scale1 = 1.0f / sqrtf(fr_x[hh] * 32.0f);
    float scale2 = 1.0f / sqrtf(fr_attn[hh] * 64.0f);

    float va[8][4];
    float vo[2][2][4];
#pragma unroll
    for (int nf = 0; nf < 8; nf++)
#pragma unroll
        for (int r = 0; r < 4; r++) va[nf][r] = 0.0f;
#pragma unroll
    for (int dt = 0; dt < 2; dt++)
#pragma unroll
        for (int nf = 0; nf < 2; nf++)
#pragma unroll
            for (int r = 0; r < 4; r++) vo[dt][nf][r] = 0.0f;

    for (int t = 0; t < TT; t++) {
        int tb = t * BB + b;
        size_t reg = (size_t)(tb * NHEAD + hh);
        const char* src = (const char*)(xsF + (reg * 8 + nt) * 4096);
#if USE_GLL
        load_lds16(src + tid * 16, (char*)&Bs[0][0][0] + tid * 16);
        load_lds16(src + tid * 16 + 4096, (char*)&Bs[0][0][0] + tid * 16 + 4096);
#else
        *(float4*)((char*)&Bs[0][0][0] + tid * 16) = *(const float4*)(src + tid * 16);
        *(float4*)((char*)&Bs[0][0][0] + tid * 16 + 4096) = *(const float4*)(src + tid * 16 + 4096);
#endif
        const _Float16* a1b = A1 + reg * 4096;
        f16x8 a1h = *(const f16x8*)(a1b + (size_t)(((w * 4 + lq) * 16 + l16) * 8));
        f16x8 a1l = *(const f16x8*)(a1b + 2048 + (size_t)(((w * 4 + lq) * 16 + l16) * 8));
        f16x8 a1ls = a1l * K2INV;    // exact exponent shift (normal range)
        __syncthreads();

        f32x4 ah[8];
#pragma unroll
        for (int nf = 0; nf < 8; nf++) ah[nf] = (f32x4){0.f, 0.f, 0.f, 0.f};
        PRIO_HI();
#pragma unroll
        for (int nf = 0; nf < 8; nf++) {
            f16x8 bf = *(const f16x8*)&Bs[lq][nf * 16 + l16][0];
            ah[nf] = __builtin_amdgcn_mfma_f32_16x16x32_f16(a1h, bf, ah[nf], 0, 0, 0);
            ah[nf] = __builtin_amdgcn_mfma_f32_16x16x32_f16(a1ls, bf, ah[nf], 0, 0, 0);
        }
        PRIO_LO();
        int pq = w * 2 + (lq >> 1);
#pragma unroll
        for (int nf = 0; nf < 8; nf++) {
            f16x4 sp;
#pragma unroll
            for (int r = 0; r < 4; r++) {
                float a = ah[nf][r] * scale1;
                float v = va[nf][r];
                v += (a - v) * 0.5f;
                float s = (v >= 1.0f) ? 1.0f : 0.0f;
                va[nf][r] = (s > 0.0f) ? 0.0f : v;
                sp[r] = (_Float16)s;
            }
            *(f16x4*)&Sat[pq][nf * 16 + l16][(lq & 1) * 4] = sp;
        }
        __syncthreads();

        const _Float16* a2b = A2 + reg * 4096;
        f32x4 oh[2][2];
#pragma unroll
        for (int dt = 0; dt < 2; dt++)
#pragma unroll
            for (int nf = 0; nf < 2; nf++) oh[dt][nf] = (f32x4){0.f, 0.f, 0.f, 0.f};
        PRIO_HI();
#pragma unroll
        for (int ks = 0; ks < 2; ks++) {
            f16x8 bf0 = *(const f16x8*)&Sat[ks * 4 + lq][w * 32 + l16][0];
            f16x8 bf1 = *(const f16x8*)&Sat[ks * 4 + lq][w * 32 + 16 + l16][0];
#pragma unroll
            for (int dt = 0; dt < 2; dt++) {
                size_t ao = (size_t)(((dt * 8 + ks * 4 + lq) * 16 + l16) * 8);
                f16x8 a2h = *(const f16x8*)(a2b + ao);
                f16x8 a2ls = *(const f16x8*)(a2b + 2048 + ao) * K2INV;
                oh[dt][0] = __builtin_amdgcn_mfma_f32_16x16x32_f16(a2h, bf0, oh[dt][0], 0, 0, 0);
                oh[dt][0] = __builtin_amdgcn_mfma_f32_16x16x32_f16(a2ls, bf0, oh[dt][0], 0, 0, 0);
                oh[dt][1] = __builtin_amdgcn_mfma_f32_16x16x32_f16(a2h, bf1, oh[dt][1], 0, 0, 0);
                oh[dt][1] = __builtin_amdgcn_mfma_f32_16x16x32_f16(a2ls, bf1, oh[dt][1], 0, 0, 0);
            }
        }
        PRIO_LO();
        _Float16* og = OsF + (reg * 8 + nt) * 4096;
#pragma unroll
        for (int dt = 0; dt < 2; dt++)
#pragma unroll
            for (int nf = 0; nf < 2; nf++) {
                f16x4 sp;
#pragma unroll
                for (int r = 0; r < 4; r++) {
                    float a = oh[dt][nf][r] * scale2;
                    float v = vo[dt][nf][r];
                    v += (a - v) * 0.5f;
                    float s = (v >= 1.0f) ? 1.0f : 0.0f;
                    vo[dt][nf][r] = (s > 0.0f) ? 0.0f : v;
                    sp[r] = (_Float16)s;
                }
                int n = w * 32 + nf * 16 + l16;
                *(f16x4*)(og + (size_t)((dt * 2 + (lq >> 1)) * 1024 + n * 8 + (lq & 1) * 4)) = sp;
            }
        __syncthreads();
    }
}

// ---------------- K4: projection GEMM via MFMA + BN2 + residual -> d_out ----------------
__global__ __launch_bounds__(256, 3) void k_proj_mfma(const _Float16* __restrict__ OsF,
                                                      const _Float16* __restrict__ WpH,
                                                      const float* __restrict__ g2,
                                                      const float* __restrict__ b2,
                                                      const float* __restrict__ m2,
                                                      const float* __restrict__ vv2,
                                                      const float* __restrict__ x,
                                                      float* __restrict__ out) {
    __shared__ __align__(16) _Float16 Bs[2][4096];   // 16 KB spike dbuf

    int bid = blockIdx.x;
    int xcd = bid & 7;
    int idx = bid >> 3;              // 0..95
    int tb = xcd * 4 + idx / 24;
    int rem = idx % 24;
    int nt = rem & 7;
    int ot = rem >> 3;               // 0..2
    int tid = threadIdx.x;
    int wave = tid >> 6;
    int lane = tid & 63;
    int l16 = lane & 15, lq = lane >> 4;
    int wn = (wave & 1) * 64, wo = (wave >> 1) * 64;   // wn: n-range, wo: o-range

    f32x4 acc[4][4];   // [fn][fo]
#pragma unroll
    for (int i = 0; i < 4; i++)
#pragma unroll
        for (int j = 0; j < 4; j++) acc[i][j] = (f32x4){0.f, 0.f, 0.f, 0.f};

    const char* bBase = (const char*)(OsF + ((size_t)tb * NHEAD * 8 + nt) * 4096);
    const _Float16* aBase = WpH + (size_t)ot * 4096 + lq * 1024 + (size_t)(wo + l16) * 8;
    int halfo = wave * 2048;
    int lo16 = lane * 16;

#if USE_GLL
#define PSTAGE(buf, kb) do {                                                   \
    const char* bS = bBase + (size_t)(kb) * (8 * 8192);                        \
    load_lds16(bS + halfo + lo16, (char*)Bs[buf] + halfo);                     \
    load_lds16(bS + halfo + 1024 + lo16, (char*)Bs[buf] + halfo + 1024);       \
} while (0)
#else
#define PSTAGE(buf, kb) do {                                                   \
    const char* bS = bBase + (size_t)(kb) * (8 * 8192);                        \
    _Pragma("unroll")                                                          \
    for (int i_ = 0; i_ < 2; ++i_) {                                           \
        int off_ = halfo + i_ * 1024 + lo16;                                   \
        *(float4*)((char*)Bs[buf] + off_) = *(const float4*)(bS + off_);       \
    }                                                                          \
} while (0)
#endif

    f16x8 af[4], afn[4];
#pragma unroll
    for (int fo = 0; fo < 4; fo++) af[fo] = *(const f16x8*)(aBase + (size_t)(fo * 16) * 8);
    PSTAGE(0, 0);
    __syncthreads();

    int cur = 0;
    for (int kb = 0; kb < 12; ++kb) {
        int kbn = (kb + 1 < 12) ? kb + 1 : kb;
        if (kb + 1 < 12) PSTAGE(cur ^ 1, kb + 1);
        const _Float16* an = aBase + (size_t)kbn * (3 * 4096);
#pragma unroll
        for (int fo = 0; fo < 4; fo++) afn[fo] = *(const f16x8*)(an + (size_t)(fo * 16) * 8);

        f16x8 bf[4];
#pragma unroll
        for (int fn = 0; fn < 4; fn++)
            bf[fn] = *(const f16x8*)&Bs[cur][(size_t)(lq * 128 + wn + fn * 16 + l16) * 8];
        PRIO_HI();
#pragma unroll
        for (int fn = 0; fn < 4; fn++)
#pragma unroll
            for (int fo = 0; fo < 4; fo++)
                acc[fn][fo] = __builtin_amdgcn_mfma_f32_16x16x32_f16(bf[fn], af[fo], acc[fn][fo], 0, 0, 0);
        PRIO_LO();

        __syncthreads();
        cur ^= 1;
#pragma unroll
        for (int fo = 0; fo < 4; fo++) af[fo] = afn[fo];
    }
#undef PSTAGE

    // epilogue: BN2 + residual, float4 over 4 consecutive n (r-index)
    size_t orow_base = (size_t)tb * CC * HWN;
#pragma unroll
    for (int fo = 0; fo < 4; fo++) {
        int o = ot * 128 + wo + fo * 16 + l16;
        float inv = g2[o] / sqrtf(vv2[o] + 1e-5f);
        float mu = m2[o];
        float bt = b2[o];
        size_t obase = orow_base + (size_t)o * HWN;
#pragma unroll
        for (int fn = 0; fn < 4; fn++) {
            size_t addr = obase + (size_t)(nt * 128 + wn + fn * 16 + lq * 4);
            float4 xv = *(const float4*)(x + addr);
            f32x4 a = acc[fn][fo];
            float4 ov;
            ov.x = (a[0] - mu) * inv + bt + xv.x;
            ov.y = (a[1] - mu) * inv + bt + xv.y;
            ov.z = (a[2] - mu) * inv + bt + xv.z;
            ov.w = (a[3] - mu) * inv + bt + xv.w;
            *(float4*)(out + addr) = ov;
        }
    }
}

extern "C" void kernel_launch(void* const* d_in, const int* in_sizes, int n_in,
                              void* d_out, int out_size, void* d_ws, size_t ws_size,
                              hipStream_t stream) {
    const float* x = (const float*)d_in[0];
    const float* w_conv = (const float*)d_in[1];
    const float* bn1_gamma = (const float*)d_in[2];
    const float* bn1_beta = (const float*)d_in[3];
    const float* bn1_mean = (const float*)d_in[4];
    const float* bn1_var = (const float*)d_in[5];
    const float* w_proj = (const float*)d_in[6];
    const float* bn2_gamma = (const float*)d_in[7];
    const float* bn2_beta = (const float*)d_in[8];
    const float* bn2_mean = (const float*)d_in[9];
    const float* bn2_var = (const float*)d_in[10];
    const float* fr_x = (const float*)d_in[11];
    const float* fr_attn = (const float*)d_in[12];

    // workspace layout
    const size_t FRAG = (size_t)16 * 192 * 4096 * 2;              // 25,165,824 (xsC; also xsF/OsF size)
    const size_t AB = (size_t)TT * BB * NHEAD * 4096 * 2;         // 3,145,728 (A1 / A2)
    const size_t WB = (size_t)KCONV * C2 * 2;                     // 9,437,184
    const size_t WPB = (size_t)CC * CC * 2;                       // 294,912
    const size_t PB = (size_t)MROWS * C2 * 4;                     // 6,291,456 per split
    _Float16* xsC = (_Float16*)d_ws;
    _Float16* xsF = (_Float16*)((char*)xsC + FRAG);
    _Float16* OsF = (_Float16*)((char*)xsF + FRAG);
    _Float16* A1 = (_Float16*)((char*)OsF + FRAG);
    _Float16* A2 = (_Float16*)((char*)A1 + AB);
    _Float16* W0 = (_Float16*)((char*)A2 + AB);
    _Float16* W1 = (_Float16*)((char*)W0 + WB);
    _Float16* WpH = (_Float16*)((char*)W1 + WB);
    char* tail = (char*)WpH + WPB;

    int KS;
    float* P;
    if (ws_size >= (size_t)(tail - (char*)d_ws) + 8 * PB) {
        KS = 8;
        P = (float*)tail;
    } else if (ws_size >= (size_t)(tail - (char*)d_ws) + 4 * PB) {
        KS = 4;
        P = (float*)tail;
    } else {
        KS = 2;                    // alias P onto OsF region (OsF written later by k_attn)
        P = (float*)OsF;
    }
    int kbPerSplit = KB_TOT / KS;

    k_pack_all<<<1188, 256, 0, stream>>>(w_conv, w_proj, W0, W1, WpH);
    k_lif1<<<dim3(16, BB * NHEAD), 256, 0, stream>>>(x, xsC, xsF);
    k_conv_mfma<<<96 * KS, 256, 0, stream>>>(xsC, W0, W1, P, KS, kbPerSplit);
    k_reduce_frag<<<32 * NHEAD, 256, 0, stream>>>(P, bn1_gamma, bn1_beta, bn1_mean, bn1_var, A1, A2, KS);
    k_attn_mfma<<<dim3(8, BB * NHEAD), 256, 0, stream>>>(xsF, A1, A2, fr_x, fr_attn, OsF);
    k_proj_mfma<<<768, 256, 0, stream>>>(OsF, WpH, bn2_gamma, bn2_beta, bn2_mean, bn2_var, x, (float*)d_out);
}